// Round 5
// baseline (1749.280 us; speedup 1.0000x reference)
//
#include <hip/hip_runtime.h>
#include <hip/hip_bf16.h>

#define BB  2048
#define TT  128
#define DD  128
#define HH1 128
#define GG1 512
#define HH2 64
#define GG2 256
#define OO  64

typedef __attribute__((ext_vector_type(8))) short  short8;
typedef __attribute__((ext_vector_type(4))) float  floatx4;

// ws byte offsets
#define OFF_WHH1 0            // bf16 [512][128]
#define OFF_WIH1 131072       // bf16 [512][128]
#define OFF_WIH2 262144       // bf16 [256][128]
#define OFF_WHH2 327680       // bf16 [256][64]
#define OFF_B1   360448       // f32 [512]  b_ih1+b_hh1
#define OFF_B2   362496       // f32 [256]  b_ih2+b_hh2
#define OFF_XBF  524288       // bf16 [2048][128][128]  x cast to bf16
#define OFF_H1S  67633152     // bf16 [2048][128][128]  layer-1 hidden seq
// total ~135 MB

__device__ __forceinline__ short f2bf(float f) {
  unsigned u = __float_as_uint(f);
  unsigned r = (u + 0x7FFFu + ((u >> 16) & 1u)) >> 16;
  return (short)r;
}
// raw v_rcp_f32 (~1 ulp) — fine vs bf16 noise; saves the IEEE-div refinement ops
__device__ __forceinline__ float sigm(float x) {
  return __builtin_amdgcn_rcpf(1.0f + __expf(-x));
}
__device__ __forceinline__ float tanh_fast(float x) {
  return 1.0f - 2.0f * __builtin_amdgcn_rcpf(1.0f + __expf(2.0f * x));
}

// ---------------- prep: bf16 weight conversion + combined biases ----------------
__global__ void k_prep(const float* __restrict__ wih1, const float* __restrict__ whh1,
                       const float* __restrict__ bih1, const float* __restrict__ bhh1,
                       const float* __restrict__ wih2, const float* __restrict__ whh2,
                       const float* __restrict__ bih2, const float* __restrict__ bhh2,
                       char* __restrict__ ws) {
  short* WHH1 = (short*)(ws + OFF_WHH1);
  short* WIH1 = (short*)(ws + OFF_WIH1);
  short* WIH2 = (short*)(ws + OFF_WIH2);
  short* WHH2 = (short*)(ws + OFF_WHH2);
  float* B1 = (float*)(ws + OFF_B1);
  float* B2 = (float*)(ws + OFF_B2);
  int idx = blockIdx.x * blockDim.x + threadIdx.x;
  int stride = gridDim.x * blockDim.x;
  for (int i = idx; i < GG1 * DD; i += stride) { WIH1[i] = f2bf(wih1[i]); WHH1[i] = f2bf(whh1[i]); }
  for (int i = idx; i < GG2 * HH1; i += stride) WIH2[i] = f2bf(wih2[i]);
  for (int i = idx; i < GG2 * HH2; i += stride) WHH2[i] = f2bf(whh2[i]);
  for (int i = idx; i < GG1; i += stride) B1[i] = bih1[i] + bhh1[i];
  for (int i = idx; i < GG2; i += stride) B2[i] = bih2[i] + bhh2[i];
}

// ---------------- xcast: x fp32 -> bf16, 8 elems/thread ----------------
__global__ __launch_bounds__(256) void k_xcast(const float* __restrict__ x,
                                               short* __restrict__ xbf) {
  size_t i = ((size_t)blockIdx.x * 256 + threadIdx.x) * 8;
  float4 a = *(const float4*)&x[i];
  float4 b = *(const float4*)&x[i + 4];
  short8 o;
  o[0] = f2bf(a.x); o[1] = f2bf(a.y); o[2] = f2bf(a.z); o[3] = f2bf(a.w);
  o[4] = f2bf(b.x); o[5] = f2bf(b.y); o[6] = f2bf(b.z); o[7] = f2bf(b.w);
  *(short8*)&xbf[i] = o;
}

// ---------------- rec1f: fused input-proj + recurrence, layer 1 ----------------
// 4 rows/block, grid 512 (2 blocks/CU); 8 waves x 64 gate cols (4 n-tiles)
__global__ __launch_bounds__(512, 4) void k_rec1f(const char* __restrict__ ws,
                                                  short* __restrict__ h1s) {
  __shared__ short hbuf[16 * 136];    // bf16 h, rows 4..15 stay 0
  __shared__ float gsm[4 * 516];      // raw preacts, padded stride
  const short* WHH = (const short*)(ws + OFF_WHH1);
  const short* WIH = (const short*)(ws + OFF_WIH1);
  const short* XBF = (const short*)(ws + OFF_XBF);
  const float* B1 = (const float*)(ws + OFF_B1);
  const int lane = threadIdx.x & 63;
  const int wv = threadIdx.x >> 6;          // 0..7
  const int col = lane & 15, quad = lane >> 4;
  const int n0 = wv * 64;
  const int r0 = blockIdx.x * 4;

  short8 wh[4][4], wx[4][4];
#pragma unroll
  for (int nt = 0; nt < 4; ++nt)
#pragma unroll
    for (int kk = 0; kk < 4; ++kk) {
      wh[nt][kk] = *(const short8*)&WHH[(n0 + nt * 16 + col) * HH1 + kk * 32 + quad * 8];
      wx[nt][kk] = *(const short8*)&WIH[(n0 + nt * 16 + col) * DD + kk * 32 + quad * 8];
    }
  float bias[4];
#pragma unroll
  for (int nt = 0; nt < 4; ++nt) bias[nt] = B1[n0 + nt * 16 + col];

  for (int i = threadIdx.x; i < 16 * 136; i += 512) hbuf[i] = 0;

  const bool aload = (col < 4);
  const short* xbase = XBF + (size_t)(r0 + (col & 3)) * TT * DD;
  short8 ax_cur[4], ax_nxt[4];
#pragma unroll
  for (int kk = 0; kk < 4; ++kk) {
    short8 z = {0, 0, 0, 0, 0, 0, 0, 0};
    ax_cur[kk] = aload ? *(const short8*)&xbase[kk * 32 + quad * 8] : z;
    ax_nxt[kk] = z;
  }

  const int j = threadIdx.x & 127;    // cell col
  const int rr = threadIdx.x >> 7;    // cell row 0..3 (one cell per thread)
  float cc = 0.f;
  __syncthreads();

  for (int t = 0; t < TT; ++t) {
    if (t + 1 < TT && aload) {
#pragma unroll
      for (int kk = 0; kk < 4; ++kk)
        ax_nxt[kk] = *(const short8*)&xbase[(t + 1) * DD + kk * 32 + quad * 8];
    }
    floatx4 acc[4];
#pragma unroll
    for (int nt = 0; nt < 4; ++nt)
      acc[nt] = (floatx4){bias[nt], bias[nt], bias[nt], bias[nt]};
    // input projection (h-independent)
#pragma unroll
    for (int kk = 0; kk < 4; ++kk)
#pragma unroll
      for (int nt = 0; nt < 4; ++nt)
        acc[nt] = __builtin_amdgcn_mfma_f32_16x16x32_bf16(ax_cur[kk], wx[nt][kk], acc[nt], 0, 0, 0);
    // recurrence
    short8 ah[4];
#pragma unroll
    for (int kk = 0; kk < 4; ++kk)
      ah[kk] = *(const short8*)&hbuf[col * 136 + kk * 32 + quad * 8];
#pragma unroll
    for (int kk = 0; kk < 4; ++kk)
#pragma unroll
      for (int nt = 0; nt < 4; ++nt)
        acc[nt] = __builtin_amdgcn_mfma_f32_16x16x32_bf16(ah[kk], wh[nt][kk], acc[nt], 0, 0, 0);

    if (quad == 0) {                  // rows 0..3 are real (quad 0 only)
#pragma unroll
      for (int nt = 0; nt < 4; ++nt)
#pragma unroll
        for (int r = 0; r < 4; ++r)
          gsm[r * 516 + n0 + nt * 16 + col] = acc[nt][r];
    }
    __syncthreads();

    {
      float i0 = gsm[rr * 516 + j],       f0 = gsm[rr * 516 + 128 + j];
      float g0 = gsm[rr * 516 + 256 + j], o0 = gsm[rr * 516 + 384 + j];
      cc = fmaf(sigm(f0), cc, sigm(i0) * tanh_fast(g0));
      float hh = sigm(o0) * tanh_fast(cc);
      short hb = f2bf(hh);
      hbuf[rr * 136 + j] = hb;
      h1s[((size_t)(r0 + rr) * TT + t) * HH1 + j] = hb;
    }
    __syncthreads();
#pragma unroll
    for (int kk = 0; kk < 4; ++kk) ax_cur[kk] = ax_nxt[kk];
  }
}

// ---------------- rec2f: fused input-proj + recurrence, layer 2 + dense head ----------------
// 4 rows/block, grid 512 (2 blocks/CU); 4 waves x 64 gate cols (4 n-tiles)
__global__ __launch_bounds__(256, 2) void k_rec2f(const char* __restrict__ ws,
                                                  const short* __restrict__ h1s,
                                                  const float* __restrict__ wd,
                                                  const float* __restrict__ bd,
                                                  float* __restrict__ out) {
  __shared__ short hbuf[16 * 72];     // bf16 h2, rows 4..15 stay 0
  __shared__ float gsm[4 * 260];      // raw preacts, padded
  __shared__ float h2f[4 * HH2];      // final fp32 h2
  const short* WHH = (const short*)(ws + OFF_WHH2);
  const short* WIH = (const short*)(ws + OFF_WIH2);
  const float* B2 = (const float*)(ws + OFF_B2);
  const int lane = threadIdx.x & 63;
  const int wv = threadIdx.x >> 6;    // 0..3
  const int col = lane & 15, quad = lane >> 4;
  const int n0 = wv * 64;
  const int r0 = blockIdx.x * 4;

  short8 wh[4][2], wx[4][4];
#pragma unroll
  for (int nt = 0; nt < 4; ++nt) {
#pragma unroll
    for (int kk = 0; kk < 2; ++kk)
      wh[nt][kk] = *(const short8*)&WHH[(n0 + nt * 16 + col) * HH2 + kk * 32 + quad * 8];
#pragma unroll
    for (int kk = 0; kk < 4; ++kk)
      wx[nt][kk] = *(const short8*)&WIH[(n0 + nt * 16 + col) * HH1 + kk * 32 + quad * 8];
  }
  float bias[4];
#pragma unroll
  for (int nt = 0; nt < 4; ++nt) bias[nt] = B2[n0 + nt * 16 + col];

  for (int i = threadIdx.x; i < 16 * 72; i += 256) hbuf[i] = 0;

  const bool aload = (col < 4);
  const short* h1base = h1s + (size_t)(r0 + (col & 3)) * TT * HH1;
  short8 ax_cur[4], ax_nxt[4];
#pragma unroll
  for (int kk = 0; kk < 4; ++kk) {
    short8 z = {0, 0, 0, 0, 0, 0, 0, 0};
    ax_cur[kk] = aload ? *(const short8*)&h1base[kk * 32 + quad * 8] : z;
    ax_nxt[kk] = z;
  }

  const int j = threadIdx.x & 63;     // cell col
  const int rr = threadIdx.x >> 6;    // cell row 0..3 (one cell per thread)
  float cc = 0.f;
  __syncthreads();

  for (int t = 0; t < TT; ++t) {
    if (t + 1 < TT && aload) {
#pragma unroll
      for (int kk = 0; kk < 4; ++kk)
        ax_nxt[kk] = *(const short8*)&h1base[(t + 1) * HH1 + kk * 32 + quad * 8];
    }
    floatx4 acc[4];
#pragma unroll
    for (int nt = 0; nt < 4; ++nt)
      acc[nt] = (floatx4){bias[nt], bias[nt], bias[nt], bias[nt]};
#pragma unroll
    for (int kk = 0; kk < 4; ++kk)
#pragma unroll
      for (int nt = 0; nt < 4; ++nt)
        acc[nt] = __builtin_amdgcn_mfma_f32_16x16x32_bf16(ax_cur[kk], wx[nt][kk], acc[nt], 0, 0, 0);
    short8 ah[2];
#pragma unroll
    for (int kk = 0; kk < 2; ++kk)
      ah[kk] = *(const short8*)&hbuf[col * 72 + kk * 32 + quad * 8];
#pragma unroll
    for (int kk = 0; kk < 2; ++kk)
#pragma unroll
      for (int nt = 0; nt < 4; ++nt)
        acc[nt] = __builtin_amdgcn_mfma_f32_16x16x32_bf16(ah[kk], wh[nt][kk], acc[nt], 0, 0, 0);

    if (quad == 0) {
#pragma unroll
      for (int nt = 0; nt < 4; ++nt)
#pragma unroll
        for (int r = 0; r < 4; ++r)
          gsm[r * 260 + n0 + nt * 16 + col] = acc[nt][r];
    }
    __syncthreads();

    {
      float i0 = gsm[rr * 260 + j],      f0 = gsm[rr * 260 + 64 + j];
      float g0 = gsm[rr * 260 + 128 + j], o0 = gsm[rr * 260 + 192 + j];
      cc = fmaf(sigm(f0), cc, sigm(i0) * tanh_fast(g0));
      float hh = sigm(o0) * tanh_fast(cc);
      hbuf[rr * 72 + j] = f2bf(hh);
      if (t == TT - 1) h2f[rr * HH2 + j] = hh;
    }
    __syncthreads();
#pragma unroll
    for (int kk = 0; kk < 4; ++kk) ax_cur[kk] = ax_nxt[kk];
  }

  // dense head (fp32)
  {
    const int o = threadIdx.x & 63;
    const int r = threadIdx.x >> 6;   // 0..3
    float acc = bd[o];
    for (int k = 0; k < HH2; ++k)
      acc = fmaf(h2f[r * HH2 + k], wd[o * HH2 + k], acc);
    out[(size_t)(r0 + r) * OO + o] = fmaxf(acc, 0.f);
  }
}

extern "C" void kernel_launch(void* const* d_in, const int* in_sizes, int n_in,
                              void* d_out, int out_size, void* d_ws, size_t ws_size,
                              hipStream_t stream) {
  const float* x       = (const float*)d_in[0];
  const float* w_ih1   = (const float*)d_in[1];
  const float* w_hh1   = (const float*)d_in[2];
  const float* b_ih1   = (const float*)d_in[3];
  const float* b_hh1   = (const float*)d_in[4];
  const float* w_ih2   = (const float*)d_in[5];
  const float* w_hh2   = (const float*)d_in[6];
  const float* b_ih2   = (const float*)d_in[7];
  const float* b_hh2   = (const float*)d_in[8];
  const float* w_dense = (const float*)d_in[9];
  const float* b_dense = (const float*)d_in[10];
  char* ws = (char*)d_ws;
  short* xbf = (short*)(ws + OFF_XBF);
  short* h1s = (short*)(ws + OFF_H1S);
  float* out = (float*)d_out;

  hipLaunchKernelGGL(k_prep, dim3(256), dim3(256), 0, stream,
                     w_ih1, w_hh1, b_ih1, b_hh1, w_ih2, w_hh2, b_ih2, b_hh2, ws);
  hipLaunchKernelGGL(k_xcast, dim3((BB * TT * DD) / (256 * 8)), dim3(256), 0, stream, x, xbf);
  hipLaunchKernelGGL(k_rec1f, dim3(BB / 4), dim3(512), 0, stream, ws, h1s);
  hipLaunchKernelGGL(k_rec2f, dim3(BB / 4), dim3(256), 0, stream, ws, h1s, w_dense, b_dense, out);
}

// Round 6
// 461.503 us; speedup vs baseline: 3.7904x; 3.7904x over previous
//
#include <hip/hip_runtime.h>
#include <hip/hip_bf16.h>

#define BB  2048
#define TT  128
#define DD  128
#define HH1 128
#define GG1 512
#define HH2 64
#define GG2 256
#define OO  64

typedef __attribute__((ext_vector_type(8))) short  short8;
typedef __attribute__((ext_vector_type(4))) float  floatx4;

// Pin a value into VGPRs: opaque asm makes rematerializing the load illegal.
#define PIN(x) asm volatile("" : "+v"(x))

// ws byte offsets
#define OFF_WHH1 0            // bf16 [512][128]
#define OFF_WIH1 131072       // bf16 [512][128]
#define OFF_WIH2 262144       // bf16 [256][128]
#define OFF_WHH2 327680       // bf16 [256][64]
#define OFF_B1   360448       // f32 [512]  b_ih1+b_hh1
#define OFF_B2   362496       // f32 [256]  b_ih2+b_hh2
#define OFF_XBF  524288       // bf16 [2048][128][128]  x cast to bf16
#define OFF_H1S  67633152     // bf16 [2048][128][128]  layer-1 hidden seq
// total ~135 MB

__device__ __forceinline__ short f2bf(float f) {
  unsigned u = __float_as_uint(f);
  unsigned r = (u + 0x7FFFu + ((u >> 16) & 1u)) >> 16;
  return (short)r;
}
__device__ __forceinline__ float sigm(float x) {
  return __builtin_amdgcn_rcpf(1.0f + __expf(-x));
}
__device__ __forceinline__ float tanh_fast(float x) {
  return 1.0f - 2.0f * __builtin_amdgcn_rcpf(1.0f + __expf(2.0f * x));
}

// ---------------- prep: bf16 weight conversion + combined biases ----------------
__global__ void k_prep(const float* __restrict__ wih1, const float* __restrict__ whh1,
                       const float* __restrict__ bih1, const float* __restrict__ bhh1,
                       const float* __restrict__ wih2, const float* __restrict__ whh2,
                       const float* __restrict__ bih2, const float* __restrict__ bhh2,
                       char* __restrict__ ws) {
  short* WHH1 = (short*)(ws + OFF_WHH1);
  short* WIH1 = (short*)(ws + OFF_WIH1);
  short* WIH2 = (short*)(ws + OFF_WIH2);
  short* WHH2 = (short*)(ws + OFF_WHH2);
  float* B1 = (float*)(ws + OFF_B1);
  float* B2 = (float*)(ws + OFF_B2);
  int idx = blockIdx.x * blockDim.x + threadIdx.x;
  int stride = gridDim.x * blockDim.x;
  for (int i = idx; i < GG1 * DD; i += stride) { WIH1[i] = f2bf(wih1[i]); WHH1[i] = f2bf(whh1[i]); }
  for (int i = idx; i < GG2 * HH1; i += stride) WIH2[i] = f2bf(wih2[i]);
  for (int i = idx; i < GG2 * HH2; i += stride) WHH2[i] = f2bf(whh2[i]);
  for (int i = idx; i < GG1; i += stride) B1[i] = bih1[i] + bhh1[i];
  for (int i = idx; i < GG2; i += stride) B2[i] = bih2[i] + bhh2[i];
}

// ---------------- xcast: x fp32 -> bf16, 8 elems/thread ----------------
__global__ __launch_bounds__(256) void k_xcast(const float* __restrict__ x,
                                               short* __restrict__ xbf) {
  size_t i = ((size_t)blockIdx.x * 256 + threadIdx.x) * 8;
  float4 a = *(const float4*)&x[i];
  float4 b = *(const float4*)&x[i + 4];
  short8 o;
  o[0] = f2bf(a.x); o[1] = f2bf(a.y); o[2] = f2bf(a.z); o[3] = f2bf(a.w);
  o[4] = f2bf(b.x); o[5] = f2bf(b.y); o[6] = f2bf(b.z); o[7] = f2bf(b.w);
  *(short8*)&xbf[i] = o;
}

// ---------------- rec1f: fused input-proj + recurrence, layer 1 ----------------
// 8 rows/block, grid 256 (1 block/CU, 8 waves); weights PINNED in registers
__global__ __launch_bounds__(512, 2) void k_rec1f(const char* __restrict__ ws,
                                                  short* __restrict__ h1s) {
  __shared__ short hbuf[16 * 136];    // bf16 h, rows 8..15 stay 0
  __shared__ float gsm[8 * 516];      // raw preacts, padded stride
  const short* WHH = (const short*)(ws + OFF_WHH1);
  const short* WIH = (const short*)(ws + OFF_WIH1);
  const short* XBF = (const short*)(ws + OFF_XBF);
  const float* B1 = (const float*)(ws + OFF_B1);
  const int lane = threadIdx.x & 63;
  const int wv = threadIdx.x >> 6;          // 0..7
  const int col = lane & 15, quad = lane >> 4;
  const int n0 = wv * 64;
  const int r0 = blockIdx.x * 8;

  short8 wh[4][4], wx[4][4];
#pragma unroll
  for (int nt = 0; nt < 4; ++nt)
#pragma unroll
    for (int kk = 0; kk < 4; ++kk) {
      wh[nt][kk] = *(const short8*)&WHH[(n0 + nt * 16 + col) * HH1 + kk * 32 + quad * 8];
      wx[nt][kk] = *(const short8*)&WIH[(n0 + nt * 16 + col) * DD + kk * 32 + quad * 8];
      PIN(wh[nt][kk]);
      PIN(wx[nt][kk]);
    }
  float bias[4];
#pragma unroll
  for (int nt = 0; nt < 4; ++nt) bias[nt] = B1[n0 + nt * 16 + col];

  for (int i = threadIdx.x; i < 16 * 136; i += 512) hbuf[i] = 0;

  const bool aload = (col < 8);
  const short* xbase = XBF + (size_t)(r0 + (col & 7)) * TT * DD;
  short8 ax_cur[4], ax_nxt[4];
#pragma unroll
  for (int kk = 0; kk < 4; ++kk) {
    short8 z = {0, 0, 0, 0, 0, 0, 0, 0};
    ax_cur[kk] = aload ? *(const short8*)&xbase[kk * 32 + quad * 8] : z;
    ax_nxt[kk] = z;
  }

  const int j = threadIdx.x & 127;    // cell col
  const int rr = threadIdx.x >> 7;    // cell rows rr, rr+4
  float cA = 0.f, cB = 0.f;
  __syncthreads();

  for (int t = 0; t < TT; ++t) {
    if (t + 1 < TT && aload) {
#pragma unroll
      for (int kk = 0; kk < 4; ++kk)
        ax_nxt[kk] = *(const short8*)&xbase[(t + 1) * DD + kk * 32 + quad * 8];
    }
    floatx4 acc[4];
#pragma unroll
    for (int nt = 0; nt < 4; ++nt)
      acc[nt] = (floatx4){bias[nt], bias[nt], bias[nt], bias[nt]};
    // input projection (h-independent)
#pragma unroll
    for (int kk = 0; kk < 4; ++kk)
#pragma unroll
      for (int nt = 0; nt < 4; ++nt)
        acc[nt] = __builtin_amdgcn_mfma_f32_16x16x32_bf16(ax_cur[kk], wx[nt][kk], acc[nt], 0, 0, 0);
    // recurrence
    short8 ah[4];
#pragma unroll
    for (int kk = 0; kk < 4; ++kk)
      ah[kk] = *(const short8*)&hbuf[col * 136 + kk * 32 + quad * 8];
#pragma unroll
    for (int kk = 0; kk < 4; ++kk)
#pragma unroll
      for (int nt = 0; nt < 4; ++nt)
        acc[nt] = __builtin_amdgcn_mfma_f32_16x16x32_bf16(ah[kk], wh[nt][kk], acc[nt], 0, 0, 0);

    if (quad < 2) {                   // rows 0..7 are real
#pragma unroll
      for (int nt = 0; nt < 4; ++nt)
#pragma unroll
        for (int r = 0; r < 4; ++r)
          gsm[(quad * 4 + r) * 516 + n0 + nt * 16 + col] = acc[nt][r];
    }
    __syncthreads();

    {
      float i0 = gsm[rr * 516 + j],       f0 = gsm[rr * 516 + 128 + j];
      float g0 = gsm[rr * 516 + 256 + j], o0 = gsm[rr * 516 + 384 + j];
      cA = fmaf(sigm(f0), cA, sigm(i0) * tanh_fast(g0));
      float hA = sigm(o0) * tanh_fast(cA);
      int r2 = rr + 4;
      float i1 = gsm[r2 * 516 + j],       f1 = gsm[r2 * 516 + 128 + j];
      float g1 = gsm[r2 * 516 + 256 + j], o1 = gsm[r2 * 516 + 384 + j];
      cB = fmaf(sigm(f1), cB, sigm(i1) * tanh_fast(g1));
      float hB = sigm(o1) * tanh_fast(cB);
      short ha = f2bf(hA), hb = f2bf(hB);
      hbuf[rr * 136 + j] = ha;
      hbuf[r2 * 136 + j] = hb;
      h1s[((size_t)(r0 + rr) * TT + t) * HH1 + j] = ha;
      h1s[((size_t)(r0 + r2) * TT + t) * HH1 + j] = hb;
    }
    __syncthreads();
#pragma unroll
    for (int kk = 0; kk < 4; ++kk) ax_cur[kk] = ax_nxt[kk];
  }
}

// ---------------- rec2f: fused input-proj + recurrence, layer 2 + dense head ----------------
// 4 rows/block, grid 512 (2 blocks/CU); weights PINNED (96 VGPRs)
__global__ __launch_bounds__(256, 2) void k_rec2f(const char* __restrict__ ws,
                                                  const short* __restrict__ h1s,
                                                  const float* __restrict__ wd,
                                                  const float* __restrict__ bd,
                                                  float* __restrict__ out) {
  __shared__ short hbuf[16 * 72];     // bf16 h2, rows 4..15 stay 0
  __shared__ float gsm[4 * 260];      // raw preacts, padded
  __shared__ float h2f[4 * HH2];      // final fp32 h2
  const short* WHH = (const short*)(ws + OFF_WHH2);
  const short* WIH = (const short*)(ws + OFF_WIH2);
  const float* B2 = (const float*)(ws + OFF_B2);
  const int lane = threadIdx.x & 63;
  const int wv = threadIdx.x >> 6;    // 0..3
  const int col = lane & 15, quad = lane >> 4;
  const int n0 = wv * 64;
  const int r0 = blockIdx.x * 4;

  short8 wh[4][2], wx[4][4];
#pragma unroll
  for (int nt = 0; nt < 4; ++nt) {
#pragma unroll
    for (int kk = 0; kk < 2; ++kk) {
      wh[nt][kk] = *(const short8*)&WHH[(n0 + nt * 16 + col) * HH2 + kk * 32 + quad * 8];
      PIN(wh[nt][kk]);
    }
#pragma unroll
    for (int kk = 0; kk < 4; ++kk) {
      wx[nt][kk] = *(const short8*)&WIH[(n0 + nt * 16 + col) * HH1 + kk * 32 + quad * 8];
      PIN(wx[nt][kk]);
    }
  }
  float bias[4];
#pragma unroll
  for (int nt = 0; nt < 4; ++nt) bias[nt] = B2[n0 + nt * 16 + col];

  for (int i = threadIdx.x; i < 16 * 72; i += 256) hbuf[i] = 0;

  const bool aload = (col < 4);
  const short* h1base = h1s + (size_t)(r0 + (col & 3)) * TT * HH1;
  short8 ax_cur[4], ax_nxt[4];
#pragma unroll
  for (int kk = 0; kk < 4; ++kk) {
    short8 z = {0, 0, 0, 0, 0, 0, 0, 0};
    ax_cur[kk] = aload ? *(const short8*)&h1base[kk * 32 + quad * 8] : z;
    ax_nxt[kk] = z;
  }

  const int j = threadIdx.x & 63;     // cell col
  const int rr = threadIdx.x >> 6;    // cell row 0..3
  float cc = 0.f;
  __syncthreads();

  for (int t = 0; t < TT; ++t) {
    if (t + 1 < TT && aload) {
#pragma unroll
      for (int kk = 0; kk < 4; ++kk)
        ax_nxt[kk] = *(const short8*)&h1base[(t + 1) * HH1 + kk * 32 + quad * 8];
    }
    floatx4 acc[4];
#pragma unroll
    for (int nt = 0; nt < 4; ++nt)
      acc[nt] = (floatx4){bias[nt], bias[nt], bias[nt], bias[nt]};
#pragma unroll
    for (int kk = 0; kk < 4; ++kk)
#pragma unroll
      for (int nt = 0; nt < 4; ++nt)
        acc[nt] = __builtin_amdgcn_mfma_f32_16x16x32_bf16(ax_cur[kk], wx[nt][kk], acc[nt], 0, 0, 0);
    short8 ah[2];
#pragma unroll
    for (int kk = 0; kk < 2; ++kk)
      ah[kk] = *(const short8*)&hbuf[col * 72 + kk * 32 + quad * 8];
#pragma unroll
    for (int kk = 0; kk < 2; ++kk)
#pragma unroll
      for (int nt = 0; nt < 4; ++nt)
        acc[nt] = __builtin_amdgcn_mfma_f32_16x16x32_bf16(ah[kk], wh[nt][kk], acc[nt], 0, 0, 0);

    if (quad == 0) {
#pragma unroll
      for (int nt = 0; nt < 4; ++nt)
#pragma unroll
        for (int r = 0; r < 4; ++r)
          gsm[r * 260 + n0 + nt * 16 + col] = acc[nt][r];
    }
    __syncthreads();

    {
      float i0 = gsm[rr * 260 + j],      f0 = gsm[rr * 260 + 64 + j];
      float g0 = gsm[rr * 260 + 128 + j], o0 = gsm[rr * 260 + 192 + j];
      cc = fmaf(sigm(f0), cc, sigm(i0) * tanh_fast(g0));
      float hh = sigm(o0) * tanh_fast(cc);
      hbuf[rr * 72 + j] = f2bf(hh);
      if (t == TT - 1) h2f[rr * HH2 + j] = hh;
    }
    __syncthreads();
#pragma unroll
    for (int kk = 0; kk < 4; ++kk) ax_cur[kk] = ax_nxt[kk];
  }

  // dense head (fp32)
  {
    const int o = threadIdx.x & 63;
    const int r = threadIdx.x >> 6;   // 0..3
    float acc = bd[o];
    for (int k = 0; k < HH2; ++k)
      acc = fmaf(h2f[r * HH2 + k], wd[o * HH2 + k], acc);
    out[(size_t)(r0 + r) * OO + o] = fmaxf(acc, 0.f);
  }
}

extern "C" void kernel_launch(void* const* d_in, const int* in_sizes, int n_in,
                              void* d_out, int out_size, void* d_ws, size_t ws_size,
                              hipStream_t stream) {
  const float* x       = (const float*)d_in[0];
  const float* w_ih1   = (const float*)d_in[1];
  const float* w_hh1   = (const float*)d_in[2];
  const float* b_ih1   = (const float*)d_in[3];
  const float* b_hh1   = (const float*)d_in[4];
  const float* w_ih2   = (const float*)d_in[5];
  const float* w_hh2   = (const float*)d_in[6];
  const float* b_ih2   = (const float*)d_in[7];
  const float* b_hh2   = (const float*)d_in[8];
  const float* w_dense = (const float*)d_in[9];
  const float* b_dense = (const float*)d_in[10];
  char* ws = (char*)d_ws;
  short* xbf = (short*)(ws + OFF_XBF);
  short* h1s = (short*)(ws + OFF_H1S);
  float* out = (float*)d_out;

  hipLaunchKernelGGL(k_prep, dim3(256), dim3(256), 0, stream,
                     w_ih1, w_hh1, b_ih1, b_hh1, w_ih2, w_hh2, b_ih2, b_hh2, ws);
  hipLaunchKernelGGL(k_xcast, dim3((BB * TT * DD) / (256 * 8)), dim3(256), 0, stream, x, xbf);
  hipLaunchKernelGGL(k_rec1f, dim3(BB / 8), dim3(512), 0, stream, ws, h1s);
  hipLaunchKernelGGL(k_rec2f, dim3(BB / 4), dim3(256), 0, stream, ws, h1s, w_dense, b_dense, out);
}